// Round 2
// baseline (1012.987 us; speedup 1.0000x reference)
//
#include <hip/hip_runtime.h>
#include <hip/hip_bf16.h>

// GCN: out[d] = dinv[d]*(sum_{e:dst=d} hs[src] + hs[d]) + b,  hs = (X@W)*dinv
// Layers 1,2: + BatchNorm(train stats, biased var) + ReLU.  Layer 3: 64->1.

#define HID 64

// ---- degree: count incoming edges (self-loop added later as +1) ----
__global__ void deg_kernel(const int* __restrict__ dst, float* __restrict__ deg, int E) {
    int tid = blockIdx.x * blockDim.x + threadIdx.x;
    int stride = gridDim.x * blockDim.x;
    for (int e = tid; e < E; e += stride)
        atomicAdd(&deg[dst[e]], 1.0f);
}

__global__ void dinv_kernel(float* __restrict__ deg, int n) {
    int tid = blockIdx.x * blockDim.x + threadIdx.x;
    int stride = gridDim.x * blockDim.x;
    for (int i = tid; i < n; i += stride)
        deg[i] = 1.0f / sqrtf(deg[i] + 1.0f);   // +1 = self loop
}

// ---- hs = (X @ W[64x64]) * dinv ;  W and 4 X-rows staged in LDS ----
__global__ void gemm64(const float* __restrict__ X, const float* __restrict__ W,
                       const float* __restrict__ dinv, float* __restrict__ out, int n) {
    __shared__ float Wl[64 * 64];
    __shared__ float xs[4][64];
    for (int i = threadIdx.x; i < 64 * 64; i += blockDim.x) Wl[i] = W[i];
    __syncthreads();
    int col = threadIdx.x & 63;
    int rl  = threadIdx.x >> 6;           // 0..3 row-group within block
    for (int base = blockIdx.x * 4; base < n; base += gridDim.x * 4) {
        int row = base + rl;
        if (row < n) xs[rl][col] = X[row * 64 + col];
        __syncthreads();
        if (row < n) {
            float acc = 0.f;
            #pragma unroll
            for (int k = 0; k < 64; ++k)
                acc = fmaf(xs[rl][k], Wl[k * 64 + col], acc);
            out[row * 64 + col] = acc * dinv[row];
        }
        __syncthreads();
    }
}

// ---- edge scatter: one edge per wave, lane = feature ----
__global__ void scatter64(const int* __restrict__ src, const int* __restrict__ dst,
                          const float* __restrict__ hs, float* __restrict__ acc, int E) {
    int lane  = threadIdx.x & 63;
    int wave  = (blockIdx.x * blockDim.x + threadIdx.x) >> 6;
    int nwave = (gridDim.x * blockDim.x) >> 6;
    for (int e = wave; e < E; e += nwave) {
        int s = src[e], d = dst[e];
        atomicAdd(&acc[d * 64 + lane], hs[s * 64 + lane]);
    }
}

// ---- y = dinv*(acc+hs)+b written in-place to acc; accumulate BN stats (f64) ----
__global__ void finalize_stats(float* __restrict__ acc, const float* __restrict__ hs,
                               const float* __restrict__ dinv, const float* __restrict__ b,
                               double* __restrict__ stats, int n) {
    int f = threadIdx.x & 63;
    float bf = b[f];
    double s = 0.0, sq = 0.0;
    int tid = blockIdx.x * blockDim.x + threadIdx.x;
    int stride = gridDim.x * blockDim.x;   // multiple of 64 -> feature fixed per thread
    for (int i = tid; i < n * 64; i += stride) {
        int row = i >> 6;
        float y = dinv[row] * (acc[i] + hs[i]) + bf;
        acc[i] = y;
        s += (double)y;
        sq += (double)y * (double)y;
    }
    __shared__ double ls[256], lq[256];
    ls[threadIdx.x] = s; lq[threadIdx.x] = sq;
    __syncthreads();
    if (threadIdx.x < 64) {
        double ts = ls[threadIdx.x] + ls[threadIdx.x + 64] + ls[threadIdx.x + 128] + ls[threadIdx.x + 192];
        double tq = lq[threadIdx.x] + lq[threadIdx.x + 64] + lq[threadIdx.x + 128] + lq[threadIdx.x + 192];
        atomicAdd(&stats[f], ts);
        atomicAdd(&stats[64 + f], tq);
    }
}

// ---- BN (biased var) + ReLU:  out = relu((y-mean)*rsqrt(var+eps)*g + bt) ----
__global__ void bn_relu(const float* __restrict__ y, const double* __restrict__ stats,
                        const float* __restrict__ g, const float* __restrict__ bt,
                        float* __restrict__ out, int n) {
    int f = threadIdx.x & 63;
    double mean = stats[f] / n;
    double var  = stats[64 + f] / n - mean * mean;
    float scale = (float)(1.0 / sqrt(var + 1e-5)) * g[f];
    float shift = bt[f] - (float)mean * scale;
    int tid = blockIdx.x * blockDim.x + threadIdx.x;
    int stride = gridDim.x * blockDim.x;
    for (int i = tid; i < n * 64; i += stride) {
        float v = y[i] * scale + shift;
        out[i] = v > 0.f ? v : 0.f;
    }
}

// ---- head: hs3[row] = dot(H[row,:], W3) * dinv[row]  (wave-reduce) ----
__global__ void gemm_w3(const float* __restrict__ H, const float* __restrict__ W3,
                        const float* __restrict__ dinv, float* __restrict__ hs3, int n) {
    int lane = threadIdx.x & 63;
    float w = W3[lane];
    int wave  = (blockIdx.x * blockDim.x + threadIdx.x) >> 6;
    int nwave = (gridDim.x * blockDim.x) >> 6;
    for (int row = wave; row < n; row += nwave) {
        float v = H[row * 64 + lane] * w;
        #pragma unroll
        for (int off = 32; off > 0; off >>= 1)
            v += __shfl_down(v, off, 64);
        if (lane == 0) hs3[row] = v * dinv[row];
    }
}

__global__ void scatter1(const int* __restrict__ src, const int* __restrict__ dst,
                         const float* __restrict__ hs3, float* __restrict__ acc3, int E) {
    int tid = blockIdx.x * blockDim.x + threadIdx.x;
    int stride = gridDim.x * blockDim.x;
    for (int e = tid; e < E; e += stride)
        atomicAdd(&acc3[dst[e]], hs3[src[e]]);
}

__global__ void final_out(const float* __restrict__ acc3, const float* __restrict__ hs3,
                          const float* __restrict__ dinv, const float* __restrict__ b3,
                          float* __restrict__ out, int n) {
    float b = b3[0];
    int tid = blockIdx.x * blockDim.x + threadIdx.x;
    int stride = gridDim.x * blockDim.x;
    for (int i = tid; i < n; i += stride)
        out[i] = dinv[i] * (acc3[i] + hs3[i]) + b;
}

extern "C" void kernel_launch(void* const* d_in, const int* in_sizes, int n_in,
                              void* d_out, int out_size, void* d_ws, size_t ws_size,
                              hipStream_t stream) {
    const float* x   = (const float*)d_in[0];
    const float* W1  = (const float*)d_in[1];
    const float* b1  = (const float*)d_in[2];
    const float* g1  = (const float*)d_in[3];
    const float* bt1 = (const float*)d_in[4];
    const float* W2  = (const float*)d_in[5];
    const float* b2  = (const float*)d_in[6];
    const float* g2  = (const float*)d_in[7];
    const float* bt2 = (const float*)d_in[8];
    const float* W3  = (const float*)d_in[9];
    const float* b3  = (const float*)d_in[10];
    const int*  edge = (const int*)d_in[11];

    int n = in_sizes[0] / 64;
    int E = in_sizes[11] / 2;
    const int* src = edge;
    const int* dst = edge + E;
    float* out = (float*)d_out;

    float* ws   = (float*)d_ws;
    float* dinv = ws;                                // n floats
    float* B    = ws + ((n + 63) & ~63);             // hs / h buffer, n*64
    float* C    = B + (size_t)n * 64;                // acc / y buffer, n*64
    double* stats = (double*)(C + (size_t)n * 64);   // 128 doubles (sum, sumsq)

    // degree -> dinv
    hipMemsetAsync(dinv, 0, n * sizeof(float), stream);
    deg_kernel<<<1024, 256, 0, stream>>>(dst, dinv, E);
    dinv_kernel<<<256, 256, 0, stream>>>(dinv, n);

    // ---- layer 1 ----
    hipMemsetAsync(C, 0, (size_t)n * 64 * sizeof(float) + 128 * sizeof(double), stream);
    gemm64<<<512, 256, 0, stream>>>(x, W1, dinv, B, n);
    scatter64<<<2048, 256, 0, stream>>>(src, dst, B, C, E);
    finalize_stats<<<1024, 256, 0, stream>>>(C, B, dinv, b1, stats, n);
    bn_relu<<<1024, 256, 0, stream>>>(C, stats, g1, bt1, B, n);

    // ---- layer 2 (gemm in-place: each row read to LDS before overwrite) ----
    hipMemsetAsync(C, 0, (size_t)n * 64 * sizeof(float) + 128 * sizeof(double), stream);
    gemm64<<<512, 256, 0, stream>>>(B, W2, dinv, B, n);
    scatter64<<<2048, 256, 0, stream>>>(src, dst, B, C, E);
    finalize_stats<<<1024, 256, 0, stream>>>(C, B, dinv, b2, stats, n);
    bn_relu<<<1024, 256, 0, stream>>>(C, stats, g2, bt2, B, n);

    // ---- layer 3 (64 -> 1) ----
    float* acc3 = C;
    float* hs3  = C + n;
    hipMemsetAsync(acc3, 0, n * sizeof(float), stream);
    gemm_w3<<<1024, 256, 0, stream>>>(B, W3, dinv, hs3, n);
    scatter1<<<2048, 256, 0, stream>>>(src, dst, hs3, acc3, E);
    final_out<<<256, 256, 0, stream>>>(acc3, hs3, dinv, b3, out, n);
}

// Round 4
// 627.380 us; speedup vs baseline: 1.6146x; 1.6146x over previous
//
#include <hip/hip_runtime.h>
#include <hip/hip_bf16.h>

// GCN via CSR gather (no f32 atomics):
//   hs = (X@W)*dinv ;  y[d] = dinv[d]*(sum_{s in N(d)} hs[s] + hs[d]) + b
//   BN stats fused into aggregation; BN-scale+ReLU fused into next GEMM load.

// ---- CSR build ----
__global__ void deg_count(const int* __restrict__ dst, int* __restrict__ degi, int E) {
    int tid = blockIdx.x * blockDim.x + threadIdx.x;
    int stride = gridDim.x * blockDim.x;
    for (int e = tid; e < E; e += stride) atomicAdd(&degi[dst[e]], 1);
}

__global__ void scan_part(const int* __restrict__ degi, int* __restrict__ part, int n) {
    __shared__ int ls[256];
    int i = blockIdx.x * 256 + threadIdx.x;
    ls[threadIdx.x] = (i < n) ? degi[i] : 0;
    __syncthreads();
    for (int o = 128; o > 0; o >>= 1) {
        if (threadIdx.x < o) ls[threadIdx.x] += ls[threadIdx.x + o];
        __syncthreads();
    }
    if (threadIdx.x == 0) part[blockIdx.x] = ls[0];
}

__global__ void scan_root(int* __restrict__ part, int nblk) {   // nblk <= 256
    __shared__ int ls[256];
    int t = threadIdx.x;
    int v = (t < nblk) ? part[t] : 0;
    ls[t] = v;
    __syncthreads();
    for (int o = 1; o < 256; o <<= 1) {
        int u = (t >= o) ? ls[t - o] : 0;
        __syncthreads();
        ls[t] += u;
        __syncthreads();
    }
    if (t < nblk) part[t] = ls[t] - v;   // exclusive
}

__global__ void scan_write(const int* __restrict__ degi, const int* __restrict__ part,
                           int* __restrict__ off, int* __restrict__ cur,
                           float* __restrict__ dinv, int n) {
    __shared__ int ls[256];
    int t = threadIdx.x, i = blockIdx.x * 256 + t;
    int d = (i < n) ? degi[i] : 0;
    ls[t] = d;
    __syncthreads();
    for (int o = 1; o < 256; o <<= 1) {
        int u = (t >= o) ? ls[t - o] : 0;
        __syncthreads();
        ls[t] += u;
        __syncthreads();
    }
    if (i < n) {
        int o0 = part[blockIdx.x] + ls[t] - d;
        off[i] = o0;
        cur[i] = o0;
        dinv[i] = rsqrtf((float)d + 1.0f);   // +1 self loop
        if (i == n - 1) off[n] = o0 + d;
    }
}

__global__ void csr_fill(const int* __restrict__ src, const int* __restrict__ dst,
                         int* __restrict__ cur, int* __restrict__ csr, int E) {
    int tid = blockIdx.x * blockDim.x + threadIdx.x;
    int stride = gridDim.x * blockDim.x;
    for (int e = tid; e < E; e += stride) {
        int p = atomicAdd(&cur[dst[e]], 1);
        csr[p] = src[e];
    }
}

// ---- hs = (maybe BN+ReLU of X) @ W[64x64] * dinv ----
__global__ void gemm64(const float* __restrict__ X, const float* __restrict__ W,
                       const double* __restrict__ stats, const float* __restrict__ g,
                       const float* __restrict__ bt, const float* __restrict__ dinv,
                       float* __restrict__ out, int n, int use_bn) {
    __shared__ float Wl[64 * 64];
    __shared__ float xs[4][64];
    int col = threadIdx.x & 63;
    int rl  = threadIdx.x >> 6;
    float scale = 1.f, shift = 0.f;
    if (use_bn) {
        double mean = stats[col] / n;
        double var  = stats[64 + col] / n - mean * mean;
        scale = (float)(1.0 / sqrt(var + 1e-5)) * g[col];
        shift = bt[col] - (float)mean * scale;
    }
    for (int i = threadIdx.x; i < 64 * 64; i += blockDim.x) Wl[i] = W[i];
    __syncthreads();
    for (int base = blockIdx.x * 4; base < n; base += gridDim.x * 4) {
        int row = base + rl;
        if (row < n) {
            float xv = X[(size_t)row * 64 + col];
            if (use_bn) xv = fmaxf(xv * scale + shift, 0.f);
            xs[rl][col] = xv;
        }
        __syncthreads();
        if (row < n) {
            float acc = 0.f;
            #pragma unroll
            for (int k = 0; k < 64; ++k)
                acc = fmaf(xs[rl][k], Wl[k * 64 + col], acc);
            out[(size_t)row * 64 + col] = acc * dinv[row];
        }
        __syncthreads();
    }
}

// ---- aggregation: wave per node, register accumulator, fused bias + BN stats ----
__global__ __launch_bounds__(256) void agg64(
        const float* __restrict__ hs, const int* __restrict__ csr,
        const int* __restrict__ off, const float* __restrict__ dinv,
        const float* __restrict__ b, float* __restrict__ y,
        double* __restrict__ stats, int n) {
    int lane  = threadIdx.x & 63;
    int wave  = (blockIdx.x * blockDim.x + threadIdx.x) >> 6;
    int nwave = (gridDim.x * blockDim.x) >> 6;
    float bf = b[lane];
    double s = 0.0, sq = 0.0;
    for (int i = wave; i < n; i += nwave) {
        int beg = off[i], end = off[i + 1];
        float acc = hs[(size_t)i * 64 + lane];       // self loop
        for (int cb = beg; cb < end; cb += 64) {
            int cnt = min(64, end - cb);
            int sv = (cb + lane < end) ? csr[cb + lane] : 0;
            for (int j = 0; j < cnt; ++j) {
                int srow = __shfl(sv, j, 64);
                acc += hs[(size_t)srow * 64 + lane];
            }
        }
        float yv = dinv[i] * acc + bf;
        y[(size_t)i * 64 + lane] = yv;
        s += (double)yv;
        sq += (double)yv * (double)yv;
    }
    __shared__ double ls[256], lq[256];
    ls[threadIdx.x] = s; lq[threadIdx.x] = sq;
    __syncthreads();
    if (threadIdx.x < 64) {
        double ts = ls[threadIdx.x] + ls[threadIdx.x + 64] + ls[threadIdx.x + 128] + ls[threadIdx.x + 192];
        double tq = lq[threadIdx.x] + lq[threadIdx.x + 64] + lq[threadIdx.x + 128] + lq[threadIdx.x + 192];
        atomicAdd(&stats[lane], ts);
        atomicAdd(&stats[64 + lane], tq);
    }
}

// ---- head: hs3 = relu(BN(y2)) . W3 * dinv  (wave-reduce) ----
__global__ void head_w3(const float* __restrict__ Y, const double* __restrict__ stats,
                        const float* __restrict__ g, const float* __restrict__ bt,
                        const float* __restrict__ W3, const float* __restrict__ dinv,
                        float* __restrict__ hs3, int n) {
    int lane = threadIdx.x & 63;
    double mean = stats[lane] / n;
    double var  = stats[64 + lane] / n - mean * mean;
    float scale = (float)(1.0 / sqrt(var + 1e-5)) * g[lane];
    float shift = bt[lane] - (float)mean * scale;
    float w = W3[lane];
    int wave  = (blockIdx.x * blockDim.x + threadIdx.x) >> 6;
    int nwave = (gridDim.x * blockDim.x) >> 6;
    for (int row = wave; row < n; row += nwave) {
        float v = fmaxf(Y[(size_t)row * 64 + lane] * scale + shift, 0.f) * w;
        #pragma unroll
        for (int o = 32; o > 0; o >>= 1) v += __shfl_down(v, o, 64);
        if (lane == 0) hs3[row] = v * dinv[row];
    }
}

// ---- layer-3 aggregation: thread per node (hs3 is L2-resident) ----
__global__ void agg1(const float* __restrict__ hs3, const int* __restrict__ csr,
                     const int* __restrict__ off, const float* __restrict__ dinv,
                     const float* __restrict__ b3, float* __restrict__ out, int n) {
    float b = b3[0];
    int tid = blockIdx.x * blockDim.x + threadIdx.x;
    int stride = gridDim.x * blockDim.x;
    for (int i = tid; i < n; i += stride) {
        float acc = hs3[i];
        int end = off[i + 1];
        for (int e = off[i]; e < end; ++e) acc += hs3[csr[e]];
        out[i] = dinv[i] * acc + b;
    }
}

extern "C" void kernel_launch(void* const* d_in, const int* in_sizes, int n_in,
                              void* d_out, int out_size, void* d_ws, size_t ws_size,
                              hipStream_t stream) {
    const float* x   = (const float*)d_in[0];
    const float* W1  = (const float*)d_in[1];
    const float* b1  = (const float*)d_in[2];
    const float* g1  = (const float*)d_in[3];
    const float* bt1 = (const float*)d_in[4];
    const float* W2  = (const float*)d_in[5];
    const float* b2  = (const float*)d_in[6];
    const float* g2  = (const float*)d_in[7];
    const float* bt2 = (const float*)d_in[8];
    const float* W3  = (const float*)d_in[9];
    const float* b3  = (const float*)d_in[10];
    const int*  edge = (const int*)d_in[11];

    int n = in_sizes[0] / 64;
    int E = in_sizes[11] / 2;
    const int* src = edge;
    const int* dst = edge + E;
    float* out = (float*)d_out;
    int nblk = (n + 255) / 256;

    // ---- workspace layout ----
    char* p = (char*)d_ws;
    double* stats = (double*)p;            p += 256 * sizeof(double);  // L1:0..127, L2:128..255
    float* dinv   = (float*)p;             p += ((n + 63) & ~63) * sizeof(float);
    int* degi     = (int*)p;               p += ((n + 63) & ~63) * sizeof(int);
    int* off      = (int*)p;               p += ((n + 64) & ~63) * sizeof(int);
    int* cur      = (int*)p;               p += ((n + 63) & ~63) * sizeof(int);
    int* part     = (int*)p;               p += 256 * sizeof(int);
    int* csr      = (int*)p;               p += (size_t)E * sizeof(int);
    float* B      = (float*)p;             p += (size_t)n * 64 * sizeof(float);
    float* C      = (float*)p;             /* n*64 floats */

    hipMemsetAsync(degi, 0, n * sizeof(int), stream);
    hipMemsetAsync(stats, 0, 256 * sizeof(double), stream);

    // CSR build
    deg_count<<<1024, 256, 0, stream>>>(dst, degi, E);
    scan_part<<<nblk, 256, 0, stream>>>(degi, part, n);
    scan_root<<<1, 256, 0, stream>>>(part, nblk);
    scan_write<<<nblk, 256, 0, stream>>>(degi, part, off, cur, dinv, n);
    csr_fill<<<1024, 256, 0, stream>>>(src, dst, cur, csr, E);

    // layer 1
    gemm64<<<512, 256, 0, stream>>>(x, W1, nullptr, nullptr, nullptr, dinv, B, n, 0);
    agg64<<<1024, 256, 0, stream>>>(B, csr, off, dinv, b1, C, stats, n);
    // layer 2 (BN1+ReLU fused into gemm input load)
    gemm64<<<512, 256, 0, stream>>>(C, W2, stats, g1, bt1, dinv, B, n, 1);
    agg64<<<1024, 256, 0, stream>>>(B, csr, off, dinv, b2, C, stats + 128, n);
    // layer 3 (BN2+ReLU fused into head)
    float* hs3 = B;
    head_w3<<<1024, 256, 0, stream>>>(C, stats + 128, g2, bt2, W3, dinv, hs3, n);
    agg1<<<512, 256, 0, stream>>>(hs3, csr, off, dinv, b3, out, n);
}

// Round 6
// 566.764 us; speedup vs baseline: 1.7873x; 1.1070x over previous
//
#include <hip/hip_runtime.h>
#include <hip/hip_bf16.h>

// GCN, CSR-gather, aggregate-then-transform:
//   y[d] = dinv[d] * ( sum_{s in N(d)} f(x[s])*dinv[s] + f(x[d])*dinv[d] ) @ W + b
// where f = identity (layer1) or BN+ReLU of previous layer (layer2).
// Gather is 4-edges-per-wave (float4/lane); 64x64 matvec done in-kernel (W in LDS).
// NOTE: self-loop term must live in slot 0 ONLY (slot-reduction sums slots).

// ---- CSR build ----
__global__ void deg_count(const int* __restrict__ dst, int* __restrict__ degi, int E) {
    int tid = blockIdx.x * blockDim.x + threadIdx.x;
    int stride = gridDim.x * blockDim.x;
    for (int e = tid; e < E; e += stride) atomicAdd(&degi[dst[e]], 1);
}

__global__ void scan_part(const int* __restrict__ degi, int* __restrict__ part, int n) {
    __shared__ int ls[256];
    int i = blockIdx.x * 256 + threadIdx.x;
    ls[threadIdx.x] = (i < n) ? degi[i] : 0;
    __syncthreads();
    for (int o = 128; o > 0; o >>= 1) {
        if (threadIdx.x < o) ls[threadIdx.x] += ls[threadIdx.x + o];
        __syncthreads();
    }
    if (threadIdx.x == 0) part[blockIdx.x] = ls[0];
}

__global__ void scan_root(int* __restrict__ part, int nblk) {   // nblk <= 256
    __shared__ int ls[256];
    int t = threadIdx.x;
    int v = (t < nblk) ? part[t] : 0;
    ls[t] = v;
    __syncthreads();
    for (int o = 1; o < 256; o <<= 1) {
        int u = (t >= o) ? ls[t - o] : 0;
        __syncthreads();
        ls[t] += u;
        __syncthreads();
    }
    if (t < nblk) part[t] = ls[t] - v;   // exclusive
}

__global__ void scan_write(const int* __restrict__ degi, const int* __restrict__ part,
                           int* __restrict__ off, int* __restrict__ cur,
                           float* __restrict__ dinv, int n) {
    __shared__ int ls[256];
    int t = threadIdx.x, i = blockIdx.x * 256 + t;
    int d = (i < n) ? degi[i] : 0;
    ls[t] = d;
    __syncthreads();
    for (int o = 1; o < 256; o <<= 1) {
        int u = (t >= o) ? ls[t - o] : 0;
        __syncthreads();
        ls[t] += u;
        __syncthreads();
    }
    if (i < n) {
        int o0 = part[blockIdx.x] + ls[t] - d;
        off[i] = o0;
        cur[i] = o0;
        dinv[i] = rsqrtf((float)d + 1.0f);   // +1 self loop
        if (i == n - 1) off[n] = o0 + d;
    }
}

__global__ void csr_fill(const int* __restrict__ src, const int* __restrict__ dst,
                         int* __restrict__ cur, int* __restrict__ csr, int E) {
    int tid = blockIdx.x * blockDim.x + threadIdx.x;
    int stride = gridDim.x * blockDim.x;
    for (int e = tid; e < E; e += stride) {
        int p = atomicAdd(&cur[dst[e]], 1);
        csr[p] = src[e];
    }
}

// ---- fused layer: gather(+BN+ReLU) -> aggregate -> @W -> +b -> *dinv -> stats ----
__global__ __launch_bounds__(256) void agg_mm(
        const float* __restrict__ Xin, const int* __restrict__ csr,
        const int* __restrict__ off, const float* __restrict__ dinv,
        const float* __restrict__ W, const float* __restrict__ bias,
        const double* __restrict__ stats_in, const float* __restrict__ g,
        const float* __restrict__ bt, double* __restrict__ stats_out,
        float* __restrict__ Yout, int n, int use_bn) {
    __shared__ float Wl[64 * 64];
    __shared__ double ls[256], lq[256];
    for (int i = threadIdx.x; i < 64 * 64; i += blockDim.x) Wl[i] = W[i];

    int lane = threadIdx.x & 63;
    int slot = lane >> 4;      // edge slot 0..3
    int fc   = lane & 15;      // feature chunk: floats 4*fc .. 4*fc+3

    float4 sc4 = {1.f, 1.f, 1.f, 1.f}, sh4 = {0.f, 0.f, 0.f, 0.f};
    if (use_bn) {
        #pragma unroll
        for (int c = 0; c < 4; ++c) {
            int f = fc * 4 + c;
            double mean = stats_in[f] / n;
            double var  = stats_in[64 + f] / n - mean * mean;
            float sc = (float)(1.0 / sqrt(var + 1e-5)) * g[f];
            float sh = bt[f] - (float)mean * sc;
            (&sc4.x)[c] = sc; (&sh4.x)[c] = sh;
        }
    }
    float bv = bias[lane];
    __syncthreads();

    int wave  = (blockIdx.x * blockDim.x + threadIdx.x) >> 6;
    int nwave = (gridDim.x * blockDim.x) >> 6;
    double s = 0.0, sq = 0.0;

    for (int i = wave; i < n; i += nwave) {
        int beg = off[i], end = off[i + 1];
        float dv = dinv[i];
        // self-loop contribution: SLOT 0 ONLY (slot reduction sums all slots)
        float4 a = {0.f, 0.f, 0.f, 0.f};
        if (slot == 0) {
            a = ((const float4*)(Xin + (size_t)i * 64))[fc];
            if (use_bn) {
                a.x = fmaxf(a.x * sc4.x + sh4.x, 0.f);
                a.y = fmaxf(a.y * sc4.y + sh4.y, 0.f);
                a.z = fmaxf(a.z * sc4.z + sh4.z, 0.f);
                a.w = fmaxf(a.w * sc4.w + sh4.w, 0.f);
            }
            a.x *= dv; a.y *= dv; a.z *= dv; a.w *= dv;
        }

        #pragma unroll 4
        for (int cb = beg + slot; cb < end; cb += 4) {
            int srow = csr[cb];                         // 16-lane broadcast
            float4 v = ((const float4*)(Xin + (size_t)srow * 64))[fc];
            if (use_bn) {
                v.x = fmaxf(v.x * sc4.x + sh4.x, 0.f);
                v.y = fmaxf(v.y * sc4.y + sh4.y, 0.f);
                v.z = fmaxf(v.z * sc4.z + sh4.z, 0.f);
                v.w = fmaxf(v.w * sc4.w + sh4.w, 0.f);
            }
            float ds = dinv[srow];                      // broadcast
            a.x = fmaf(v.x, ds, a.x);
            a.y = fmaf(v.y, ds, a.y);
            a.z = fmaf(v.z, ds, a.z);
            a.w = fmaf(v.w, ds, a.w);
        }
        // reduce across 4 edge slots (all lanes end with totals for their chunk)
        a.x += __shfl_xor(a.x, 16, 64); a.y += __shfl_xor(a.y, 16, 64);
        a.z += __shfl_xor(a.z, 16, 64); a.w += __shfl_xor(a.w, 16, 64);
        a.x += __shfl_xor(a.x, 32, 64); a.y += __shfl_xor(a.y, 32, 64);
        a.z += __shfl_xor(a.z, 32, 64); a.w += __shfl_xor(a.w, 32, 64);

        // matvec: out col = lane;  feature k lives in component k&3 of lane k>>2
        float acc = 0.f;
        #pragma unroll
        for (int k = 0; k < 64; ++k) {
            float comp = (k & 3) == 0 ? a.x : (k & 3) == 1 ? a.y : (k & 3) == 2 ? a.z : a.w;
            float ak = __shfl(comp, k >> 2, 64);
            acc = fmaf(ak, Wl[k * 64 + lane], acc);
        }
        float yv = dv * acc + bv;
        Yout[(size_t)i * 64 + lane] = yv;
        s += (double)yv;
        sq += (double)yv * (double)yv;
    }

    ls[threadIdx.x] = s; lq[threadIdx.x] = sq;
    __syncthreads();
    if (threadIdx.x < 64) {
        double ts = ls[threadIdx.x] + ls[threadIdx.x + 64] + ls[threadIdx.x + 128] + ls[threadIdx.x + 192];
        double tq = lq[threadIdx.x] + lq[threadIdx.x + 64] + lq[threadIdx.x + 128] + lq[threadIdx.x + 192];
        atomicAdd(&stats_out[threadIdx.x], ts);
        atomicAdd(&stats_out[64 + threadIdx.x], tq);
    }
}

// ---- head: hs3[row] = (relu(BN(y2[row])) . W3) * dinv[row] ----
__global__ void head_w3(const float* __restrict__ Y, const double* __restrict__ stats,
                        const float* __restrict__ g, const float* __restrict__ bt,
                        const float* __restrict__ W3, const float* __restrict__ dinv,
                        float* __restrict__ hs3, int n) {
    int lane = threadIdx.x & 63;
    double mean = stats[lane] / n;
    double var  = stats[64 + lane] / n - mean * mean;
    float scale = (float)(1.0 / sqrt(var + 1e-5)) * g[lane];
    float shift = bt[lane] - (float)mean * scale;
    float w = W3[lane];
    int wave  = (blockIdx.x * blockDim.x + threadIdx.x) >> 6;
    int nwave = (gridDim.x * blockDim.x) >> 6;
    for (int row = wave; row < n; row += nwave) {
        float v = fmaxf(Y[(size_t)row * 64 + lane] * scale + shift, 0.f) * w;
        #pragma unroll
        for (int o = 32; o > 0; o >>= 1) v += __shfl_down(v, o, 64);
        if (lane == 0) hs3[row] = v * dinv[row];
    }
}

// ---- layer-3 aggregation: wave per node, lane-parallel edge gather ----
__global__ void agg1(const float* __restrict__ hs3, const int* __restrict__ csr,
                     const int* __restrict__ off, const float* __restrict__ dinv,
                     const float* __restrict__ b3, float* __restrict__ out, int n) {
    float b = b3[0];
    int lane  = threadIdx.x & 63;
    int wave  = (blockIdx.x * blockDim.x + threadIdx.x) >> 6;
    int nwave = (gridDim.x * blockDim.x) >> 6;
    for (int i = wave; i < n; i += nwave) {
        int beg = off[i], end = off[i + 1];
        float acc = 0.f;
        for (int e = beg + lane; e < end; e += 64) acc += hs3[csr[e]];
        #pragma unroll
        for (int o = 32; o > 0; o >>= 1) acc += __shfl_down(acc, o, 64);
        if (lane == 0) out[i] = dinv[i] * (acc + hs3[i]) + b;
    }
}

extern "C" void kernel_launch(void* const* d_in, const int* in_sizes, int n_in,
                              void* d_out, int out_size, void* d_ws, size_t ws_size,
                              hipStream_t stream) {
    const float* x   = (const float*)d_in[0];
    const float* W1  = (const float*)d_in[1];
    const float* b1  = (const float*)d_in[2];
    const float* g1  = (const float*)d_in[3];
    const float* bt1 = (const float*)d_in[4];
    const float* W2  = (const float*)d_in[5];
    const float* b2  = (const float*)d_in[6];
    const float* g2  = (const float*)d_in[7];
    const float* bt2 = (const float*)d_in[8];
    const float* W3  = (const float*)d_in[9];
    const float* b3  = (const float*)d_in[10];
    const int*  edge = (const int*)d_in[11];

    int n = in_sizes[0] / 64;
    int E = in_sizes[11] / 2;
    const int* src = edge;
    const int* dst = edge + E;
    float* out = (float*)d_out;
    int nblk = (n + 255) / 256;

    // ---- workspace layout ----
    char* p = (char*)d_ws;
    double* stats = (double*)p;            p += 256 * sizeof(double);  // L1:0..127, L2:128..255
    float* dinv   = (float*)p;             p += ((n + 63) & ~63) * sizeof(float);
    int* degi     = (int*)p;               p += ((n + 63) & ~63) * sizeof(int);
    int* off      = (int*)p;               p += ((n + 64) & ~63) * sizeof(int);
    int* cur      = (int*)p;               p += ((n + 63) & ~63) * sizeof(int);
    int* part     = (int*)p;               p += 256 * sizeof(int);
    int* csr      = (int*)p;               p += (size_t)E * sizeof(int);
    float* Y1     = (float*)p;             p += (size_t)n * 64 * sizeof(float);
    float* Y2     = (float*)p;             p += (size_t)n * 64 * sizeof(float);
    float* hs3    = (float*)p;             /* n floats */

    hipMemsetAsync(degi, 0, n * sizeof(int), stream);
    hipMemsetAsync(stats, 0, 256 * sizeof(double), stream);

    // CSR build
    deg_count<<<2048, 256, 0, stream>>>(dst, degi, E);
    scan_part<<<nblk, 256, 0, stream>>>(degi, part, n);
    scan_root<<<1, 256, 0, stream>>>(part, nblk);
    scan_write<<<nblk, 256, 0, stream>>>(degi, part, off, cur, dinv, n);
    csr_fill<<<2048, 256, 0, stream>>>(src, dst, cur, csr, E);

    // layer 1: gather x
    agg_mm<<<2048, 256, 0, stream>>>(x, csr, off, dinv, W1, b1,
                                     nullptr, nullptr, nullptr, stats, Y1, n, 0);
    // layer 2: gather y1 with BN1+ReLU fused
    agg_mm<<<2048, 256, 0, stream>>>(Y1, csr, off, dinv, W2, b2,
                                     stats, g1, bt1, stats + 128, Y2, n, 1);
    // layer 3: BN2+ReLU+W3 -> hs3 ; scalar aggregate
    head_w3<<<2048, 256, 0, stream>>>(Y2, stats + 128, g2, bt2, W3, dinv, hs3, n);
    agg1<<<2048, 256, 0, stream>>>(hs3, csr, off, dinv, b3, out, n);
}

// Round 7
// 486.022 us; speedup vs baseline: 2.0842x; 1.1661x over previous
//
#include <hip/hip_runtime.h>
#include <hip/hip_bf16.h>

// GCN, CSR-gather, pre-transformed tables:
//   T = f(X)*dinv  (f = identity layer1, BN+ReLU layer2)
//   y[d] = dinv[d] * ( sum_{s in N(d)} T[s] + T[d] ) @ W + b
// agg_mm: 8 edge-slots x float8/lane, 2-node dual-stream; pure-sum inner loop.

// ---- CSR build ----
__global__ void deg_count(const int* __restrict__ dst, int* __restrict__ degi, int E) {
    int tid = blockIdx.x * blockDim.x + threadIdx.x;
    int stride = gridDim.x * blockDim.x;
    for (int e = tid; e < E; e += stride) atomicAdd(&degi[dst[e]], 1);
}

__global__ void scan_part(const int* __restrict__ degi, int* __restrict__ part, int n) {
    __shared__ int ls[256];
    int i = blockIdx.x * 256 + threadIdx.x;
    ls[threadIdx.x] = (i < n) ? degi[i] : 0;
    __syncthreads();
    for (int o = 128; o > 0; o >>= 1) {
        if (threadIdx.x < o) ls[threadIdx.x] += ls[threadIdx.x + o];
        __syncthreads();
    }
    if (threadIdx.x == 0) part[blockIdx.x] = ls[0];
}

__global__ void scan_root(int* __restrict__ part, int nblk) {   // nblk <= 256
    __shared__ int ls[256];
    int t = threadIdx.x;
    int v = (t < nblk) ? part[t] : 0;
    ls[t] = v;
    __syncthreads();
    for (int o = 1; o < 256; o <<= 1) {
        int u = (t >= o) ? ls[t - o] : 0;
        __syncthreads();
        ls[t] += u;
        __syncthreads();
    }
    if (t < nblk) part[t] = ls[t] - v;   // exclusive
}

__global__ void scan_write(const int* __restrict__ degi, const int* __restrict__ part,
                           int* __restrict__ off, int* __restrict__ cur,
                           float* __restrict__ dinv, int n) {
    __shared__ int ls[256];
    int t = threadIdx.x, i = blockIdx.x * 256 + t;
    int d = (i < n) ? degi[i] : 0;
    ls[t] = d;
    __syncthreads();
    for (int o = 1; o < 256; o <<= 1) {
        int u = (t >= o) ? ls[t - o] : 0;
        __syncthreads();
        ls[t] += u;
        __syncthreads();
    }
    if (i < n) {
        int o0 = part[blockIdx.x] + ls[t] - d;
        off[i] = o0;
        cur[i] = o0;
        dinv[i] = rsqrtf((float)d + 1.0f);   // +1 self loop
        if (i == n - 1) off[n] = o0 + d;
    }
}

__global__ void csr_fill(const int* __restrict__ src, const int* __restrict__ dst,
                         int* __restrict__ cur, int* __restrict__ csr, int E) {
    int tid = blockIdx.x * blockDim.x + threadIdx.x;
    int stride = gridDim.x * blockDim.x;
    for (int e = tid; e < E; e += stride) {
        int p = atomicAdd(&cur[dst[e]], 1);
        csr[p] = src[e];
    }
}

// ---- T1 = x * dinv ----
__global__ void prescale(const float* __restrict__ x, const float* __restrict__ dinv,
                         float* __restrict__ T, int n) {
    int tid = blockIdx.x * blockDim.x + threadIdx.x;
    int stride = gridDim.x * blockDim.x;
    int total = n * 16;            // float4 count
    const float4* x4 = (const float4*)x;
    float4* T4 = (float4*)T;
    for (int i = tid; i < total; i += stride) {
        float4 v = x4[i];
        float dv = dinv[i >> 4];
        v.x *= dv; v.y *= dv; v.z *= dv; v.w *= dv;
        T4[i] = v;
    }
}

// ---- T2 = relu(BN(y)) * dinv ----
__global__ void bnrelu_scale(const float* __restrict__ Y, const double* __restrict__ stats,
                             const float* __restrict__ g, const float* __restrict__ bt,
                             const float* __restrict__ dinv, float* __restrict__ T, int n) {
    int f = threadIdx.x & 63;
    double mean = stats[f] / n;
    double var  = stats[64 + f] / n - mean * mean;
    float scale = (float)(1.0 / sqrt(var + 1e-5)) * g[f];
    float shift = bt[f] - (float)mean * scale;
    int tid = blockIdx.x * blockDim.x + threadIdx.x;
    int stride = gridDim.x * blockDim.x;   // multiple of 64
    for (int i = tid; i < n * 64; i += stride) {
        float v = fmaxf(Y[i] * scale + shift, 0.f);
        T[i] = v * dinv[i >> 6];
    }
}

// ---- fused layer: pure gather-sum -> @W -> *dinv + b -> stats ----
__global__ __launch_bounds__(256) void agg_mm(
        const float4* __restrict__ T4, const int* __restrict__ csr,
        const int* __restrict__ off, const float* __restrict__ dinv,
        const float* __restrict__ W, const float* __restrict__ bias,
        double* __restrict__ stats_out, float* __restrict__ Y, int n) {
    __shared__ float Wl[64 * 64];
    __shared__ double ls[256], lq[256];
    for (int t = threadIdx.x; t < 64 * 64; t += blockDim.x) Wl[t] = W[t];

    int lane = threadIdx.x & 63;
    int slot = lane >> 3;      // 8 edge slots
    int fl   = lane & 7;       // floats 8*fl .. 8*fl+7 (two float4)
    float bv = bias[lane];
    __syncthreads();

    int wave  = (blockIdx.x * blockDim.x + threadIdx.x) >> 6;
    int nwave = (gridDim.x * blockDim.x) >> 6;
    double s = 0.0, sq = 0.0;

    for (int i0 = wave; i0 < n; i0 += 2 * nwave) {
        int i1 = i0 + nwave;
        bool has1 = (i1 < n);
        int b0 = off[i0], e0 = off[i0 + 1];
        int b1 = 0, e1 = 0;
        if (has1) { b1 = off[i1]; e1 = off[i1 + 1]; }

        float4 a0l = {0,0,0,0}, a0h = {0,0,0,0};
        float4 a1l = {0,0,0,0}, a1h = {0,0,0,0};
        if (slot == 0) {                       // self term in slot 0 only
            a0l = T4[(size_t)i0 * 16 + fl * 2];
            a0h = T4[(size_t)i0 * 16 + fl * 2 + 1];
            if (has1) {
                a1l = T4[(size_t)i1 * 16 + fl * 2];
                a1h = T4[(size_t)i1 * 16 + fl * 2 + 1];
            }
        }

        int c0 = b0 + slot, c1 = b1 + slot;
        while (c0 < e0 || (has1 && c1 < e1)) {
            if (c0 < e0) {
                int sr = csr[c0];
                float4 vl = T4[(size_t)sr * 16 + fl * 2];
                float4 vh = T4[(size_t)sr * 16 + fl * 2 + 1];
                a0l.x += vl.x; a0l.y += vl.y; a0l.z += vl.z; a0l.w += vl.w;
                a0h.x += vh.x; a0h.y += vh.y; a0h.z += vh.z; a0h.w += vh.w;
                c0 += 8;
            }
            if (has1 && c1 < e1) {
                int sr = csr[c1];
                float4 vl = T4[(size_t)sr * 16 + fl * 2];
                float4 vh = T4[(size_t)sr * 16 + fl * 2 + 1];
                a1l.x += vl.x; a1l.y += vl.y; a1l.z += vl.z; a1l.w += vl.w;
                a1h.x += vh.x; a1h.y += vh.y; a1h.z += vh.z; a1h.w += vh.w;
                c1 += 8;
            }
        }

        // reduce across the 8 slots (lane bits 3,4,5)
        #pragma unroll
        for (int m = 8; m <= 32; m <<= 1) {
            a0l.x += __shfl_xor(a0l.x, m, 64); a0l.y += __shfl_xor(a0l.y, m, 64);
            a0l.z += __shfl_xor(a0l.z, m, 64); a0l.w += __shfl_xor(a0l.w, m, 64);
            a0h.x += __shfl_xor(a0h.x, m, 64); a0h.y += __shfl_xor(a0h.y, m, 64);
            a0h.z += __shfl_xor(a0h.z, m, 64); a0h.w += __shfl_xor(a0h.w, m, 64);
            a1l.x += __shfl_xor(a1l.x, m, 64); a1l.y += __shfl_xor(a1l.y, m, 64);
            a1l.z += __shfl_xor(a1l.z, m, 64); a1l.w += __shfl_xor(a1l.w, m, 64);
            a1h.x += __shfl_xor(a1h.x, m, 64); a1h.y += __shfl_xor(a1h.y, m, 64);
            a1h.z += __shfl_xor(a1h.z, m, 64); a1h.w += __shfl_xor(a1h.w, m, 64);
        }

        // matvec: feature k owned by lane (k>>3), component (k&7)
        float acc0 = 0.f, acc1 = 0.f;
        #pragma unroll
        for (int k = 0; k < 64; ++k) {
            const int c = k & 7, sl = k >> 3;
            float comp0 = c == 0 ? a0l.x : c == 1 ? a0l.y : c == 2 ? a0l.z : c == 3 ? a0l.w
                        : c == 4 ? a0h.x : c == 5 ? a0h.y : c == 6 ? a0h.z : a0h.w;
            float comp1 = c == 0 ? a1l.x : c == 1 ? a1l.y : c == 2 ? a1l.z : c == 3 ? a1l.w
                        : c == 4 ? a1h.x : c == 5 ? a1h.y : c == 6 ? a1h.z : a1h.w;
            float wk = Wl[k * 64 + lane];
            acc0 = fmaf(__shfl(comp0, sl, 64), wk, acc0);
            acc1 = fmaf(__shfl(comp1, sl, 64), wk, acc1);
        }
        float y0 = dinv[i0] * acc0 + bv;
        Y[(size_t)i0 * 64 + lane] = y0;
        s += (double)y0; sq += (double)y0 * (double)y0;
        if (has1) {
            float y1v = dinv[i1] * acc1 + bv;
            Y[(size_t)i1 * 64 + lane] = y1v;
            s += (double)y1v; sq += (double)y1v * (double)y1v;
        }
    }

    ls[threadIdx.x] = s; lq[threadIdx.x] = sq;
    __syncthreads();
    if (threadIdx.x < 64) {
        double ts = ls[threadIdx.x] + ls[threadIdx.x + 64] + ls[threadIdx.x + 128] + ls[threadIdx.x + 192];
        double tq = lq[threadIdx.x] + lq[threadIdx.x + 64] + lq[threadIdx.x + 128] + lq[threadIdx.x + 192];
        atomicAdd(&stats_out[threadIdx.x], ts);
        atomicAdd(&stats_out[64 + threadIdx.x], tq);
    }
}

// ---- head: hs3[row] = (relu(BN(y2[row])) . W3) * dinv[row] ----
__global__ void head_w3(const float* __restrict__ Y, const double* __restrict__ stats,
                        const float* __restrict__ g, const float* __restrict__ bt,
                        const float* __restrict__ W3, const float* __restrict__ dinv,
                        float* __restrict__ hs3, int n) {
    int lane = threadIdx.x & 63;
    double mean = stats[lane] / n;
    double var  = stats[64 + lane] / n - mean * mean;
    float scale = (float)(1.0 / sqrt(var + 1e-5)) * g[lane];
    float shift = bt[lane] - (float)mean * scale;
    float w = W3[lane];
    int wave  = (blockIdx.x * blockDim.x + threadIdx.x) >> 6;
    int nwave = (gridDim.x * blockDim.x) >> 6;
    for (int row = wave; row < n; row += nwave) {
        float v = fmaxf(Y[(size_t)row * 64 + lane] * scale + shift, 0.f) * w;
        #pragma unroll
        for (int o = 32; o > 0; o >>= 1) v += __shfl_down(v, o, 64);
        if (lane == 0) hs3[row] = v * dinv[row];
    }
}

// ---- layer-3 aggregation: wave per node, lane-parallel edge gather ----
__global__ void agg1(const float* __restrict__ hs3, const int* __restrict__ csr,
                     const int* __restrict__ off, const float* __restrict__ dinv,
                     const float* __restrict__ b3, float* __restrict__ out, int n) {
    float b = b3[0];
    int lane  = threadIdx.x & 63;
    int wave  = (blockIdx.x * blockDim.x + threadIdx.x) >> 6;
    int nwave = (gridDim.x * blockDim.x) >> 6;
    for (int i = wave; i < n; i += nwave) {
        int beg = off[i], end = off[i + 1];
        float acc = 0.f;
        for (int e = beg + lane; e < end; e += 64) acc += hs3[csr[e]];
        #pragma unroll
        for (int o = 32; o > 0; o >>= 1) acc += __shfl_down(acc, o, 64);
        if (lane == 0) out[i] = dinv[i] * (acc + hs3[i]) + b;
    }
}

extern "C" void kernel_launch(void* const* d_in, const int* in_sizes, int n_in,
                              void* d_out, int out_size, void* d_ws, size_t ws_size,
                              hipStream_t stream) {
    const float* x   = (const float*)d_in[0];
    const float* W1  = (const float*)d_in[1];
    const float* b1  = (const float*)d_in[2];
    const float* g1  = (const float*)d_in[3];
    const float* bt1 = (const float*)d_in[4];
    const float* W2  = (const float*)d_in[5];
    const float* b2  = (const float*)d_in[6];
    const float* g2  = (const float*)d_in[7];
    const float* bt2 = (const float*)d_in[8];
    const float* W3  = (const float*)d_in[9];
    const float* b3  = (const float*)d_in[10];
    const int*  edge = (const int*)d_in[11];

    int n = in_sizes[0] / 64;
    int E = in_sizes[11] / 2;
    const int* src = edge;
    const int* dst = edge + E;
    float* out = (float*)d_out;
    int nblk = (n + 255) / 256;

    // ---- workspace ----
    char* p = (char*)d_ws;
    double* stats = (double*)p;            p += 256 * sizeof(double);  // L1:0..127, L2:128..255
    float* dinv   = (float*)p;             p += ((n + 63) & ~63) * sizeof(float);
    int* degi     = (int*)p;               p += ((n + 63) & ~63) * sizeof(int);
    int* off      = (int*)p;               p += ((n + 64) & ~63) * sizeof(int);
    int* cur      = (int*)p;               p += ((n + 63) & ~63) * sizeof(int);
    int* part     = (int*)p;               p += 256 * sizeof(int);
    int* csr      = (int*)p;               p += (size_t)E * sizeof(int);
    float* A      = (float*)p;             p += (size_t)n * 64 * sizeof(float);  // T1 / T2
    float* B      = (float*)p;             p += (size_t)n * 64 * sizeof(float);  // Y1 / Y2
    float* hs3    = (float*)p;             /* n floats */

    hipMemsetAsync(degi, 0, n * sizeof(int), stream);
    hipMemsetAsync(stats, 0, 256 * sizeof(double), stream);

    // CSR build
    deg_count<<<2048, 256, 0, stream>>>(dst, degi, E);
    scan_part<<<nblk, 256, 0, stream>>>(degi, part, n);
    scan_root<<<1, 256, 0, stream>>>(part, nblk);
    scan_write<<<nblk, 256, 0, stream>>>(degi, part, off, cur, dinv, n);
    csr_fill<<<2048, 256, 0, stream>>>(src, dst, cur, csr, E);

    // layer 1: T1 = x*dinv ; y1 = dinv*(gather-sum T1)@W1 + b1
    prescale<<<1024, 256, 0, stream>>>(x, dinv, A, n);
    agg_mm<<<2048, 256, 0, stream>>>((const float4*)A, csr, off, dinv, W1, b1,
                                     stats, B, n);
    // layer 2: T2 = relu(BN1(y1))*dinv ; y2 = dinv*(gather-sum T2)@W2 + b2
    bnrelu_scale<<<1024, 256, 0, stream>>>(B, stats, g1, bt1, dinv, A, n);
    agg_mm<<<2048, 256, 0, stream>>>((const float4*)A, csr, off, dinv, W2, b2,
                                     stats + 128, B, n);
    // layer 3
    head_w3<<<2048, 256, 0, stream>>>(B, stats + 128, g2, bt2, W3, dinv, hs3, n);
    agg1<<<2048, 256, 0, stream>>>(hs3, csr, off, dinv, b3, out, n);
}